// Round 1
// baseline (23176.253 us; speedup 1.0000x reference)
//
#include <hip/hip_runtime.h>
#include <hip/hip_fp16.h>

// LSTM forecaster: B=256, T=512, D_IN=64, H=1024, out = h_final @ Wout + bout.
// Strategy: persistent cooperative kernel, grid=256 (1 WG/CU), 4 waves/WG.
//  - WG (m,n): batch rows [64m,64m+64), hidden units [16n,16n+16) -> 64 gate cols
//    (W columns repacked fp16, gate-interleaved (i,f,g,o per unit), fragment-contiguous).
//  - Waves K-split (1088 = 34 chunks of 32, wave w takes chunks c%4==w).
//  - MFMA f16 16x16x32, f32 accum; frags loaded direct global->reg (L2-hot).
//  - Cross-wave reduction via 64KB XOR-swizzled LDS (conflict-free), activations in f32,
//    cell state in registers across all 512 steps, h in double-buffered fp16 global buf.
//  - One atomic grid barrier per step (double buffer removes the second barrier).

#define B_TOT 256
#define T_STEPS 512
#define HID 1024
#define NCHUNK 34   // 1088/32
#define GRID 256
#define NTHR 256

typedef __attribute__((ext_vector_type(8))) _Float16 half8;
typedef __attribute__((ext_vector_type(4))) float f32x4;

__device__ __forceinline__ float sigm(float v) { return 1.0f / (1.0f + __expf(-v)); }
__device__ __forceinline__ float tanh_fast(float v) { return 2.0f / (1.0f + __expf(-2.0f * v)) - 1.0f; }

// Pack W [1088][4096] f32 -> Wp fp16 [n(64)][kb(136)][col(64)][kin(8)]
// col c of group n maps to original column (c&3)*1024 + n*16 + (c>>2)  (gate-interleaved).
__global__ void pack_w(const float* __restrict__ W, _Float16* __restrict__ Wp) {
    int idx = blockIdx.x * 256 + threadIdx.x;
    const int total = 64 * 136 * 64;
    if (idx >= total) return;
    int col = idx & 63;
    int kb = (idx >> 6) % 136;
    int n = (idx >> 6) / 136;
    int oc = ((col & 3) << 10) + (n << 4) + (col >> 2);
    const float* src = W + (size_t)(kb * 8) * 4096 + oc;
    _Float16* dst = Wp + (size_t)idx * 8;
#pragma unroll
    for (int j = 0; j < 8; j++) dst[j] = (_Float16)src[(size_t)j * 4096];
}

__global__ void __launch_bounds__(NTHR, 1) lstm_persist(
    const float* __restrict__ x,      // [256][512][64] f32
    const _Float16* __restrict__ Wp,  // packed W fp16
    const float* __restrict__ bias,   // [4096] f32
    _Float16* __restrict__ hbuf,      // [2][128][256][8] fp16  (kb, b, kin)
    float* __restrict__ hfinal,       // [256][1024] f32
    unsigned int* bar)                // [0]=count [1]=gen
{
    __shared__ float P[4 * 64 * 64];  // 64 KiB, XOR-swizzled partials [wave][c][b]

    int wg = blockIdx.x;
    // XCD-aware mapping: XCD x gets n in [8x,8x+8) for all 4 m -> W hot set 1.1MB/XCD L2.
    int xcd = wg & 7, slot = wg >> 3;
    int n = (xcd << 3) + (slot & 7);  // 0..63
    int m = slot >> 3;                 // 0..3
    int B0 = m << 6;

    int tid = threadIdx.x;
    int wave = tid >> 6;
    int lane = tid & 63;
    int l15 = lane & 15, l4 = lane >> 4;
    int bb = tid & 63;
    int u0 = tid >> 6;

    // per-thread bias registers: pair q -> (b=bb, u=u0+4q), gates i,f,g,o
    float breg[4][4];
#pragma unroll
    for (int q = 0; q < 4; q++) {
        int u = u0 + (q << 2);
#pragma unroll
        for (int g = 0; g < 4; g++) breg[q][g] = bias[(g << 10) + (n << 4) + u];
    }

    float cst[4] = {0.f, 0.f, 0.f, 0.f};  // cell state, f32, lives here all 512 steps

    const size_t HBUF_ELEMS = (size_t)128 * 256 * 8;
    const _Float16* WpBase = Wp + (size_t)n * 136 * 64 * 8;

    for (int t = 0; t < T_STEPS; t++) {
        const _Float16* cur = hbuf + (size_t)(t & 1) * HBUF_ELEMS;
        _Float16* nxt = hbuf + (size_t)((t + 1) & 1) * HBUF_ELEMS;

        f32x4 acc[4][4];
#pragma unroll
        for (int i = 0; i < 4; i++)
#pragma unroll
            for (int j = 0; j < 4; j++) acc[i][j] = (f32x4){0.f, 0.f, 0.f, 0.f};

        // K loop: wave w handles chunks cc = w, w+4, ... (<34)
        for (int cc = wave; cc < NCHUNK; cc += 4) {
            int kb = (cc << 2) + l4;  // 8-elem k-block index, 0..135
            half8 bf[4];
            const _Float16* wp = WpBase + ((size_t)kb << 9);  // kb*64*8
#pragma unroll
            for (int nn = 0; nn < 4; nn++)
                bf[nn] = *(const half8*)(wp + (((nn << 4) + l15) << 3));

            half8 af[4];
            if (cc >= 2) {
                // h part: k-64, block kb-8
                const _Float16* hp = cur + (((size_t)(kb - 8) << 8) + B0 + l15) * 8;
#pragma unroll
                for (int mm = 0; mm < 4; mm++)
                    af[mm] = *(const half8*)(hp + (mm << 7));
            } else {
                // x part: d = kb*8 + j
#pragma unroll
                for (int mm = 0; mm < 4; mm++) {
                    const float* xp = x + ((size_t)(B0 + (mm << 4) + l15) * T_STEPS + t) * 64 + (kb << 3);
                    f32x4 lo = *(const f32x4*)xp;
                    f32x4 hi = *(const f32x4*)(xp + 4);
                    half8 v;
                    v[0] = (_Float16)lo[0]; v[1] = (_Float16)lo[1];
                    v[2] = (_Float16)lo[2]; v[3] = (_Float16)lo[3];
                    v[4] = (_Float16)hi[0]; v[5] = (_Float16)hi[1];
                    v[6] = (_Float16)hi[2]; v[7] = (_Float16)hi[3];
                    af[mm] = v;
                }
            }
#pragma unroll
            for (int mm = 0; mm < 4; mm++)
#pragma unroll
                for (int nn = 0; nn < 4; nn++)
                    acc[mm][nn] = __builtin_amdgcn_mfma_f32_16x16x32_f16(af[mm], bf[nn], acc[mm][nn], 0, 0, 0);
        }

        // ---- cross-wave reduction through LDS (XOR-swizzled, conflict-free) ----
        __syncthreads();  // previous step's activation reads of P are done
#pragma unroll
        for (int mm = 0; mm < 4; mm++)
#pragma unroll
            for (int nn = 0; nn < 4; nn++) {
                int c = (nn << 4) + l15;                    // col within 64
                int bblk = (mm << 2) + l4;                  // (b0>>2), b0 = mm*16 + l4*4
                int word = (((wave << 6) + c) << 6) + (((bblk ^ l15) & 15) << 2);
                *(f32x4*)&P[word] = acc[mm][nn];
            }
        __syncthreads();

        // ---- activations + state update: thread handles 4 (b,u) pairs ----
#pragma unroll
        for (int q = 0; q < 4; q++) {
            int u = u0 + (q << 2);
            float g4[4];
#pragma unroll
            for (int g = 0; g < 4; g++) {
                int c = (u << 2) + g;
                int word = (c << 6) + (((((bb >> 2) ^ c) & 15) << 2) | (bb & 3));
                float s = breg[q][g];
#pragma unroll
                for (int w = 0; w < 4; w++) s += P[(w << 12) + word];
                g4[g] = s;
            }
            float ig = sigm(g4[0]);
            float fg = sigm(g4[1]);
            float gg = tanh_fast(g4[2]);
            float og = sigm(g4[3]);
            float cv = fg * cst[q] + ig * gg;
            cst[q] = cv;
            float hv = og * tanh_fast(cv);
            int ug = (n << 4) + u;
            nxt[((size_t)(ug >> 3) * 256 + B0 + bb) * 8 + (ug & 7)] = (_Float16)hv;
            if (t == T_STEPS - 1) hfinal[(size_t)(B0 + bb) * HID + ug] = hv;
        }

        // ---- grid barrier (one per step; h is double-buffered) ----
        __syncthreads();
        if (tid == 0) {
            __threadfence();  // release h writes
            unsigned int g = __hip_atomic_load(&bar[1], __ATOMIC_RELAXED, __HIP_MEMORY_SCOPE_AGENT);
            unsigned int arrived =
                __hip_atomic_fetch_add(&bar[0], 1u, __ATOMIC_ACQ_REL, __HIP_MEMORY_SCOPE_AGENT) + 1u;
            if (arrived == (unsigned int)GRID) {
                __hip_atomic_store(&bar[0], 0u, __ATOMIC_RELAXED, __HIP_MEMORY_SCOPE_AGENT);
                __hip_atomic_store(&bar[1], g + 1u, __ATOMIC_RELEASE, __HIP_MEMORY_SCOPE_AGENT);
            } else {
                while (__hip_atomic_load(&bar[1], __ATOMIC_ACQUIRE, __HIP_MEMORY_SCOPE_AGENT) == g) {
                    __builtin_amdgcn_s_sleep(4);
                }
            }
            __threadfence();  // acquire: invalidate CU L1 before next step's h reads
        }
        __syncthreads();
    }
}

// out[b][j] = bout[j] + sum_k hfinal[b][k] * Wout[k][j]   (256 blocks x 64 threads)
__global__ void proj_kernel(const float* __restrict__ hfinal, const float* __restrict__ Wout,
                            const float* __restrict__ bout, float* __restrict__ out) {
    int b = blockIdx.x;
    int l = threadIdx.x;
    float acc[24];
#pragma unroll
    for (int j = 0; j < 24; j++) acc[j] = 0.f;
    for (int i = 0; i < 16; i++) {
        int k = i * 64 + l;
        float h = hfinal[(size_t)b * HID + k];
        const float* wr = Wout + (size_t)k * 24;
#pragma unroll
        for (int j = 0; j < 24; j++) acc[j] += h * wr[j];
    }
    __shared__ float red[24][65];
#pragma unroll
    for (int j = 0; j < 24; j++) red[j][l] = acc[j];
    __syncthreads();
    if (l < 24) {
        float s = bout[l];
#pragma unroll
        for (int i = 0; i < 64; i++) s += red[l][i];
        out[b * 24 + l] = s;
    }
}

extern "C" void kernel_launch(void* const* d_in, const int* in_sizes, int n_in,
                              void* d_out, int out_size, void* d_ws, size_t ws_size,
                              hipStream_t stream) {
    const float* x = (const float*)d_in[0];     // [256][512][64]
    const float* W = (const float*)d_in[1];     // [1088][4096]
    const float* b = (const float*)d_in[2];     // [4096]
    const float* Wout = (const float*)d_in[3];  // [1024][24]
    const float* bout = (const float*)d_in[4];  // [24]
    float* out = (float*)d_out;

    char* ws = (char*)d_ws;
    _Float16* Wp = (_Float16*)ws;                              // 8,912,896 B
    _Float16* hbuf = (_Float16*)(ws + 8912896);                // 1,048,576 B ([2][128][256][8])
    float* hfinal = (float*)(ws + 8912896 + 1048576);          // 1,048,576 B
    unsigned int* bar = (unsigned int*)(ws + 8912896 + 2097152);  // 8 B

    // zero h buffer 0 (h_init = 0) and the barrier state, every call
    hipMemsetAsync(hbuf, 0, (size_t)128 * 256 * 8 * sizeof(_Float16), stream);
    hipMemsetAsync(bar, 0, 2 * sizeof(unsigned int), stream);

    pack_w<<<(64 * 136 * 64 + 255) / 256, 256, 0, stream>>>(W, Wp);

    void* args[6];
    args[0] = (void*)&x;
    args[1] = (void*)&Wp;
    args[2] = (void*)&b;
    args[3] = (void*)&hbuf;
    args[4] = (void*)&hfinal;
    args[5] = (void*)&bar;
    hipLaunchCooperativeKernel((void*)lstm_persist, dim3(GRID), dim3(NTHR), args, 0, stream);

    proj_kernel<<<256, 64, 0, stream>>>(hfinal, Wout, bout, out);
}

// Round 2
// 4322.109 us; speedup vs baseline: 5.3623x; 5.3623x over previous
//
#include <hip/hip_runtime.h>
#include <hip/hip_fp16.h>

// LSTM forecaster: B=256, T=512, D_IN=64, H=1024, out = h_final @ Wout + bout.
// Persistent cooperative kernel, grid=256 (1 WG/CU), 4 waves/WG.
// Round 2 changes vs round 1 (which was 45us/step, fence/latency-bound):
//  - NO __threadfence (was full L2 wb+inv per block per step, evicting W).
//    h exchange via relaxed agent-scope atomics (sc-flag cache-bypass, MALL-coherent);
//    W/x/bias stay normally cached -> W stays L2-resident across all 512 steps.
//  - Hierarchical monotonic grid barrier (8 groups x 32 + root), no resets.
//  - Depth-2 software-pipelined K loop (double frag regs) to hide MALL latency.
//  - One 8B atomic h-store per thread (units 4*u0..4*u0+3 packed).

#define T_STEPS 512
#define HID 1024
#define NCHUNK 34   // 1088/32
#define GRID 256
#define NTHR 256

typedef __attribute__((ext_vector_type(8))) _Float16 half8;
typedef __attribute__((ext_vector_type(4))) float f32x4;

__device__ __forceinline__ float sigm(float v) { return 1.0f / (1.0f + __expf(-v)); }
__device__ __forceinline__ float tanh_fast(float v) { return 2.0f / (1.0f + __expf(-2.0f * v)) - 1.0f; }

// Pack W [1088][4096] f32 -> Wp fp16 [n(64)][kb(136)][col(64)][kin(8)]
// col c of group n maps to original column (c&3)*1024 + n*16 + (c>>2)  (gate-interleaved).
__global__ void pack_w(const float* __restrict__ W, _Float16* __restrict__ Wp) {
    int idx = blockIdx.x * 256 + threadIdx.x;
    const int total = 64 * 136 * 64;
    if (idx >= total) return;
    int col = idx & 63;
    int kb = (idx >> 6) % 136;
    int n = (idx >> 6) / 136;
    int oc = ((col & 3) << 10) + (n << 4) + (col >> 2);
    const float* src = W + (size_t)(kb * 8) * 4096 + oc;
    _Float16* dst = Wp + (size_t)idx * 8;
#pragma unroll
    for (int j = 0; j < 8; j++) dst[j] = (_Float16)src[(size_t)j * 4096];
}

__global__ void __launch_bounds__(NTHR, 1) lstm_persist(
    const float* __restrict__ x,      // [256][512][64] f32
    const _Float16* __restrict__ Wp,  // packed W fp16
    const float* __restrict__ bias,   // [4096] f32
    _Float16* __restrict__ hbuf,      // [2][128][256][8] fp16  (kb, b, kin)
    float* __restrict__ hfinal,       // [256][1024] f32
    unsigned int* bar)                // hierarchical barrier state (monotonic)
{
    __shared__ float P[4 * 64 * 64];  // 64 KiB, XOR-swizzled partials [wave][c][b]

    int wg = blockIdx.x;
    // XCD-aware mapping: XCD x gets n in [8x,8x+8) for all 4 m -> W hot set 1.1MB/XCD L2.
    int xcd = wg & 7, slot = wg >> 3;
    int n = (xcd << 3) + (slot & 7);  // 0..63
    int m = slot >> 3;                 // 0..3
    int B0 = m << 6;

    int tid = threadIdx.x;
    int wave = tid >> 6;
    int lane = tid & 63;
    int l15 = lane & 15, l4 = lane >> 4;
    int bb = tid & 63;
    int u0 = tid >> 6;

    // per-thread bias registers: q -> (b=bb, u=4*u0+q), gates i,f,g,o
    float breg[4][4];
#pragma unroll
    for (int q = 0; q < 4; q++) {
        int u = (u0 << 2) + q;
#pragma unroll
        for (int g = 0; g < 4; g++) breg[q][g] = bias[(g << 10) + (n << 4) + u];
    }

    float cst[4] = {0.f, 0.f, 0.f, 0.f};  // cell state, f32, lives here all 512 steps

    const size_t HBUF_ELEMS = (size_t)128 * 256 * 8;
    const _Float16* WpBase = Wp + (size_t)n * 136 * 64 * 8;

    for (int t = 0; t < T_STEPS; t++) {
        const _Float16* cur = hbuf + (size_t)(t & 1) * HBUF_ELEMS;
        _Float16* nxt = hbuf + (size_t)((t + 1) & 1) * HBUF_ELEMS;

        f32x4 acc[4][4];
#pragma unroll
        for (int i = 0; i < 4; i++)
#pragma unroll
            for (int j = 0; j < 4; j++) acc[i][j] = (f32x4){0.f, 0.f, 0.f, 0.f};

        // fragment loader: chunk cc covers k in [32cc, 32cc+32)
        auto LOAD = [&](int cc, half8* af, half8* bf) {
            int kb = (cc << 2) + l4;  // 8-elem k-block index, 0..135
            const _Float16* wp = WpBase + ((size_t)kb << 9);  // cached (L2-resident)
#pragma unroll
            for (int nn = 0; nn < 4; nn++)
                bf[nn] = *(const half8*)(wp + (((nn << 4) + l15) << 3));
            if (cc >= 2) {
                // h part, coherent (MALL) loads: 2x u64 per fragment
                unsigned long long* hp =
                    (unsigned long long*)(cur + (((size_t)(kb - 8) << 8) + B0 + l15) * 8);
#pragma unroll
                for (int mm = 0; mm < 4; mm++) {
                    union { unsigned long long u[2]; half8 h; } cv;
                    cv.u[0] = __hip_atomic_load(hp + (mm << 5), __ATOMIC_RELAXED,
                                                __HIP_MEMORY_SCOPE_AGENT);
                    cv.u[1] = __hip_atomic_load(hp + (mm << 5) + 1, __ATOMIC_RELAXED,
                                                __HIP_MEMORY_SCOPE_AGENT);
                    af[mm] = cv.h;
                }
            } else {
                // x part: d = kb*8 + j, cached loads + f32->f16 convert
#pragma unroll
                for (int mm = 0; mm < 4; mm++) {
                    const float* xp =
                        x + ((size_t)(B0 + (mm << 4) + l15) * T_STEPS + t) * 64 + (kb << 3);
                    f32x4 lo = *(const f32x4*)xp;
                    f32x4 hi = *(const f32x4*)(xp + 4);
                    half8 v;
                    v[0] = (_Float16)lo[0]; v[1] = (_Float16)lo[1];
                    v[2] = (_Float16)lo[2]; v[3] = (_Float16)lo[3];
                    v[4] = (_Float16)hi[0]; v[5] = (_Float16)hi[1];
                    v[6] = (_Float16)hi[2]; v[7] = (_Float16)hi[3];
                    af[mm] = v;
                }
            }
        };
        auto MM = [&](half8* af, half8* bf) {
#pragma unroll
            for (int mm = 0; mm < 4; mm++)
#pragma unroll
                for (int nn = 0; nn < 4; nn++)
                    acc[mm][nn] = __builtin_amdgcn_mfma_f32_16x16x32_f16(af[mm], bf[nn],
                                                                         acc[mm][nn], 0, 0, 0);
        };

        // K loop, depth-2 pipelined: wave w handles chunks w, w+4, ... (<34)
        {
            half8 aA[4], bA[4], aB[4], bB[4];
            int cc = wave;
            LOAD(cc, aA, bA);
            for (;;) {
                int n1 = cc + 4;
                if (n1 < NCHUNK) LOAD(n1, aB, bB);
                MM(aA, bA);
                if (n1 >= NCHUNK) break;
                int n2 = cc + 8;
                if (n2 < NCHUNK) LOAD(n2, aA, bA);
                MM(aB, bB);
                if (n2 >= NCHUNK) break;
                cc = n2;
            }
        }

        // ---- cross-wave reduction through LDS (XOR-swizzled, conflict-free) ----
        __syncthreads();  // previous step's activation reads of P are done
#pragma unroll
        for (int mm = 0; mm < 4; mm++)
#pragma unroll
            for (int nn = 0; nn < 4; nn++) {
                int c = (nn << 4) + l15;                    // col within 64
                int bblk = (mm << 2) + l4;                  // b0>>2
                int word = (((wave << 6) + c) << 6) + (((bblk ^ l15) & 15) << 2);
                *(f32x4*)&P[word] = acc[mm][nn];
            }
        __syncthreads();

        // ---- activations + state update: thread handles (b=bb, u=4*u0+q) ----
        union { _Float16 h4[4]; unsigned long long u; } hs;
        float hvf[4];
#pragma unroll
        for (int q = 0; q < 4; q++) {
            int u = (u0 << 2) + q;
            float g4[4];
#pragma unroll
            for (int g = 0; g < 4; g++) {
                int c = (u << 2) + g;
                int word = (c << 6) + (((((bb >> 2) ^ c) & 15) << 2) | (bb & 3));
                float s = breg[q][g];
#pragma unroll
                for (int w = 0; w < 4; w++) s += P[(w << 12) + word];
                g4[g] = s;
            }
            float ig = sigm(g4[0]);
            float fg = sigm(g4[1]);
            float gg = tanh_fast(g4[2]);
            float og = sigm(g4[3]);
            float cv = fg * cst[q] + ig * gg;
            cst[q] = cv;
            float hv = og * tanh_fast(cv);
            hs.h4[q] = (_Float16)hv;
            hvf[q] = hv;
        }
        {
            int ug0 = (n << 4) + (u0 << 2);
            unsigned long long* dst =
                (unsigned long long*)(nxt + ((size_t)(ug0 >> 3) * 256 + B0 + bb) * 8 + (ug0 & 7));
            __hip_atomic_store(dst, hs.u, __ATOMIC_RELAXED, __HIP_MEMORY_SCOPE_AGENT);
        }
        if (t == T_STEPS - 1) {
            int ug0 = (n << 4) + (u0 << 2);
            f32x4 hv4 = {hvf[0], hvf[1], hvf[2], hvf[3]};
            *(f32x4*)&hfinal[(size_t)(B0 + bb) * HID + ug0] = hv4;
            break;  // no barrier needed after last step
        }

        // ---- hierarchical grid barrier (monotonic counters, agent-scope atomics) ----
        asm volatile("s_waitcnt vmcnt(0)" ::: "memory");  // own h-store ack'd at MALL
        __syncthreads();
        if (tid == 0) {
            unsigned int* cnt = bar + ((wg >> 5) << 6);  // 8 groups of 32, 256B apart
            unsigned int* cnt2 = bar + 520;
            unsigned int* flag = bar + 576;
            unsigned int pos = __hip_atomic_fetch_add(cnt, 1u, __ATOMIC_RELAXED,
                                                      __HIP_MEMORY_SCOPE_AGENT);
            if (pos == (unsigned int)(32 * (t + 1) - 1)) {
                unsigned int d = __hip_atomic_fetch_add(cnt2, 1u, __ATOMIC_RELAXED,
                                                        __HIP_MEMORY_SCOPE_AGENT);
                if (d == (unsigned int)(8 * (t + 1) - 1)) {
                    __hip_atomic_store(flag, (unsigned int)(t + 1), __ATOMIC_RELAXED,
                                       __HIP_MEMORY_SCOPE_AGENT);
                }
            }
            while (__hip_atomic_load(flag, __ATOMIC_RELAXED, __HIP_MEMORY_SCOPE_AGENT) <
                   (unsigned int)(t + 1)) {
                __builtin_amdgcn_s_sleep(2);
            }
            asm volatile("" ::: "memory");
        }
        __syncthreads();
    }
}

// out[b][j] = bout[j] + sum_k hfinal[b][k] * Wout[k][j]   (256 blocks x 64 threads)
__global__ void proj_kernel(const float* __restrict__ hfinal, const float* __restrict__ Wout,
                            const float* __restrict__ bout, float* __restrict__ out) {
    int b = blockIdx.x;
    int l = threadIdx.x;
    float acc[24];
#pragma unroll
    for (int j = 0; j < 24; j++) acc[j] = 0.f;
    for (int i = 0; i < 16; i++) {
        int k = i * 64 + l;
        float h = hfinal[(size_t)b * HID + k];
        const float* wr = Wout + (size_t)k * 24;
#pragma unroll
        for (int j = 0; j < 24; j++) acc[j] += h * wr[j];
    }
    __shared__ float red[24][65];
#pragma unroll
    for (int j = 0; j < 24; j++) red[j][l] = acc[j];
    __syncthreads();
    if (l < 24) {
        float s = bout[l];
#pragma unroll
        for (int i = 0; i < 64; i++) s += red[l][i];
        out[b * 24 + l] = s;
    }
}

extern "C" void kernel_launch(void* const* d_in, const int* in_sizes, int n_in,
                              void* d_out, int out_size, void* d_ws, size_t ws_size,
                              hipStream_t stream) {
    const float* x = (const float*)d_in[0];     // [256][512][64]
    const float* W = (const float*)d_in[1];     // [1088][4096]
    const float* b = (const float*)d_in[2];     // [4096]
    const float* Wout = (const float*)d_in[3];  // [1024][24]
    const float* bout = (const float*)d_in[4];  // [24]
    float* out = (float*)d_out;

    char* ws = (char*)d_ws;
    _Float16* Wp = (_Float16*)ws;                                 // 8,912,896 B
    _Float16* hbuf = (_Float16*)(ws + 8912896);                   // 1,048,576 B
    float* hfinal = (float*)(ws + 8912896 + 1048576);             // 1,048,576 B
    unsigned int* bar = (unsigned int*)(ws + 8912896 + 2097152);  // 4096 B

    // zero h buffer 0 (h_init = 0) and barrier state, every call (graph-replay safe)
    hipMemsetAsync(hbuf, 0, (size_t)128 * 256 * 8 * sizeof(_Float16), stream);
    hipMemsetAsync(bar, 0, 4096, stream);

    pack_w<<<(64 * 136 * 64 + 255) / 256, 256, 0, stream>>>(W, Wp);

    void* args[6];
    args[0] = (void*)&x;
    args[1] = (void*)&Wp;
    args[2] = (void*)&b;
    args[3] = (void*)&hbuf;
    args[4] = (void*)&hfinal;
    args[5] = (void*)&bar;
    hipLaunchCooperativeKernel((void*)lstm_persist, dim3(GRID), dim3(NTHR), args, 0, stream);

    proj_kernel<<<256, 64, 0, stream>>>(hfinal, Wout, bout, out);
}

// Round 3
// 3688.982 us; speedup vs baseline: 6.2826x; 1.1716x over previous
//
#include <hip/hip_runtime.h>
#include <hip/hip_fp16.h>

// LSTM forecaster: B=256, T=512, D_IN=64, H=1024, out = h_final @ Wout + bout.
// Persistent cooperative kernel, grid=256 (1 WG/CU), 8 waves/WG (512 thr).
// Round 3 vs round 2 (8.4us/step, latency-bound):
//  - 8-way K-split -> W fragments REGISTER-RESIDENT (64 VGPR/thread, loaded once).
//    K-loop = issue 32 MALL h-loads, one latency, 64 MFMAs. 2 waves/SIMD overlap.
//  - x(t+1)@Wx precomputed into acc BEFORE the grid barrier (h-independent).
//  - RMW-free barrier: per-WG arrival word (64B apart); threads 256..511 each
//    spin on one WG's word -> one fabric round trip after last arrival.
//  - Two-pass LDS reduce in 64KB: waves 0-3 write planes, waves 4-7 add in place,
//    activation reads 4 partials. XOR-swizzled, conflict-free.

#define T_STEPS 512
#define HID 1024
#define GRID 256
#define NTHR 512

typedef __attribute__((ext_vector_type(8))) _Float16 half8;
typedef __attribute__((ext_vector_type(4))) float f32x4;
typedef __attribute__((ext_vector_type(2))) float f32x2;

__device__ __forceinline__ float sigm(float v) { return 1.0f / (1.0f + __expf(-v)); }
__device__ __forceinline__ float tanh_fast(float v) { return 2.0f / (1.0f + __expf(-2.0f * v)) - 1.0f; }

// Pack W [1088][4096] f32 -> Wp fp16 [n(64)][kb(136)][col(64)][kin(8)]
// col c of group n maps to original column (c&3)*1024 + n*16 + (c>>2)  (gate-interleaved).
__global__ void pack_w(const float* __restrict__ W, _Float16* __restrict__ Wp) {
    int idx = blockIdx.x * 256 + threadIdx.x;
    const int total = 64 * 136 * 64;
    if (idx >= total) return;
    int col = idx & 63;
    int kb = (idx >> 6) % 136;
    int n = (idx >> 6) / 136;
    int oc = ((col & 3) << 10) + (n << 4) + (col >> 2);
    const float* src = W + (size_t)(kb * 8) * 4096 + oc;
    _Float16* dst = Wp + (size_t)idx * 8;
#pragma unroll
    for (int j = 0; j < 8; j++) dst[j] = (_Float16)src[(size_t)j * 4096];
}

__global__ void __launch_bounds__(NTHR, 2) lstm_persist(
    const float* __restrict__ x,      // [256][512][64] f32
    const _Float16* __restrict__ Wp,  // packed W fp16
    const float* __restrict__ bias,   // [4096] f32
    _Float16* __restrict__ hbuf,      // [2][128][256][8] fp16  (kb, b, kin)
    float* __restrict__ hfinal,       // [256][1024] f32
    unsigned int* bar)                // [256] arrival words, 64B apart
{
    __shared__ float P[4 * 64 * 64];  // 64 KiB, 4 planes, XOR-swizzled

    int wg = blockIdx.x;
    // XCD-aware mapping: XCD x gets n in [8x,8x+8) for all 4 m.
    int xcd = wg & 7, slot = wg >> 3;
    int n = (xcd << 3) + (slot & 7);  // 0..63
    int m = slot >> 3;                 // 0..3
    int B0 = m << 6;

    int tid = threadIdx.x;
    int wave = tid >> 6;   // 0..7
    int lane = tid & 63;
    int l15 = lane & 15, l4 = lane >> 4;
    int bb = tid & 63;
    int u0 = tid >> 6;     // 0..7 (activation: units 2*u0, 2*u0+1)

    // per-thread bias: q -> (b=bb, u=2*u0+q), gates i,f,g,o
    float breg[2][4];
#pragma unroll
    for (int q = 0; q < 2; q++) {
        int u = (u0 << 1) + q;
#pragma unroll
        for (int g = 0; g < 4; g++) breg[q][g] = bias[(g << 10) + (n << 4) + u];
    }

    float cst[2] = {0.f, 0.f};

    const size_t HB = (size_t)128 * 256 * 8;
    const _Float16* WpBase = Wp + (size_t)n * 136 * 64 * 8;

    // ---- W prologue: this wave's 4 h-chunks -> registers, reused all 512 steps ----
    // wave<2: h-chunks {w+8,w+16,w+24,w+32} (x chunk w handled separately)
    // wave>=2: {w, w+8, w+16, w+24}.  Union covers chunks 2..33.
    int hc[4];
#pragma unroll
    for (int j = 0; j < 4; j++) hc[j] = (wave < 2) ? (wave + 8 * (j + 1)) : (wave + 8 * j);
    half8 wfr[4][4];
#pragma unroll
    for (int j = 0; j < 4; j++) {
        int kb = (hc[j] << 2) + l4;  // 8..135
        const _Float16* wp = WpBase + ((size_t)kb << 9);
#pragma unroll
        for (int nn = 0; nn < 4; nn++) wfr[j][nn] = *(const half8*)(wp + (((nn << 4) + l15) << 3));
    }

    f32x4 acc[4][4];
#pragma unroll
    for (int i = 0; i < 4; i++)
#pragma unroll
        for (int j = 0; j < 4; j++) acc[i][j] = (f32x4){0.f, 0.f, 0.f, 0.f};

    // x(tt) @ Wx into acc (waves 0,1 only; chunk=wave covers k in [32w,32w+32))
    auto XPREP = [&](int tt) {
        if (wave < 2) {
            int kb = (wave << 2) + l4;  // 0..7
            half8 bx[4];
            const _Float16* wp = WpBase + ((size_t)kb << 9);
#pragma unroll
            for (int nn = 0; nn < 4; nn++) bx[nn] = *(const half8*)(wp + (((nn << 4) + l15) << 3));
#pragma unroll
            for (int mm = 0; mm < 4; mm++) {
                const float* xp = x + ((size_t)(B0 + (mm << 4) + l15) * T_STEPS + tt) * 64 + (kb << 3);
                f32x4 lo = *(const f32x4*)xp;
                f32x4 hi = *(const f32x4*)(xp + 4);
                half8 v;
                v[0] = (_Float16)lo[0]; v[1] = (_Float16)lo[1];
                v[2] = (_Float16)lo[2]; v[3] = (_Float16)lo[3];
                v[4] = (_Float16)hi[0]; v[5] = (_Float16)hi[1];
                v[6] = (_Float16)hi[2]; v[7] = (_Float16)hi[3];
#pragma unroll
                for (int nn = 0; nn < 4; nn++)
                    acc[mm][nn] = __builtin_amdgcn_mfma_f32_16x16x32_f16(v, bx[nn], acc[mm][nn], 0, 0, 0);
            }
        }
    };

    XPREP(0);

    for (int t = 0; t < T_STEPS; t++) {
        const _Float16* cur = hbuf + (size_t)(t & 1) * HB;
        _Float16* nxt = hbuf + (size_t)((t + 1) & 1) * HB;

        // ---- issue ALL h loads (coherent, MALL), then MFMA against register W ----
        half8 ah[4][4];
#pragma unroll
        for (int j = 0; j < 4; j++) {
            int kb = (hc[j] << 2) + l4;  // 8..135
            unsigned long long* hp =
                (unsigned long long*)(cur + (((size_t)(kb - 8) << 8) + B0 + l15) * 8);
#pragma unroll
            for (int mm = 0; mm < 4; mm++) {
                union { unsigned long long u[2]; half8 h; } cv;
                cv.u[0] = __hip_atomic_load(hp + (mm << 5), __ATOMIC_RELAXED, __HIP_MEMORY_SCOPE_AGENT);
                cv.u[1] = __hip_atomic_load(hp + (mm << 5) + 1, __ATOMIC_RELAXED, __HIP_MEMORY_SCOPE_AGENT);
                ah[j][mm] = cv.h;
            }
        }
#pragma unroll
        for (int j = 0; j < 4; j++)
#pragma unroll
            for (int mm = 0; mm < 4; mm++)
#pragma unroll
                for (int nn = 0; nn < 4; nn++)
                    acc[mm][nn] = __builtin_amdgcn_mfma_f32_16x16x32_f16(ah[j][mm], wfr[j][nn],
                                                                         acc[mm][nn], 0, 0, 0);

        // ---- two-pass cross-wave reduction, 4 planes of 16KB, XOR-swizzled ----
        // (previous step's P reads finished before the end-of-step barrier syncthreads)
        if (wave < 4) {
#pragma unroll
            for (int mm = 0; mm < 4; mm++)
#pragma unroll
                for (int nn = 0; nn < 4; nn++) {
                    int c = (nn << 4) + l15;
                    int bblk = (mm << 2) + l4;
                    int word = (((wave << 6) + c) << 6) + (((bblk ^ l15) & 15) << 2);
                    *(f32x4*)&P[word] = acc[mm][nn];
                }
        }
        __syncthreads();
        if (wave >= 4) {
            int pw = wave - 4;
#pragma unroll
            for (int mm = 0; mm < 4; mm++)
#pragma unroll
                for (int nn = 0; nn < 4; nn++) {
                    int c = (nn << 4) + l15;
                    int bblk = (mm << 2) + l4;
                    int word = (((pw << 6) + c) << 6) + (((bblk ^ l15) & 15) << 2);
                    f32x4 v = *(f32x4*)&P[word];
                    v += acc[mm][nn];
                    *(f32x4*)&P[word] = v;
                }
        }
        __syncthreads();

        // ---- activations: thread handles (b=bb, u=2*u0+q), q=0,1 ----
        union { _Float16 h2[2]; unsigned int u; } hs;
        float hvf[2];
#pragma unroll
        for (int q = 0; q < 2; q++) {
            int u = (u0 << 1) + q;
            float g4[4];
#pragma unroll
            for (int g = 0; g < 4; g++) {
                int c = (u << 2) + g;
                int word = (c << 6) + (((((bb >> 2) ^ c) & 15) << 2) | (bb & 3));
                float s = breg[q][g];
#pragma unroll
                for (int w = 0; w < 4; w++) s += P[(w << 12) + word];
                g4[g] = s;
            }
            float ig = sigm(g4[0]);
            float fg = sigm(g4[1]);
            float gg = tanh_fast(g4[2]);
            float og = sigm(g4[3]);
            float cv = fg * cst[q] + ig * gg;
            cst[q] = cv;
            float hv = og * tanh_fast(cv);
            hs.h2[q] = (_Float16)hv;
            hvf[q] = hv;
        }
        int ug0 = (n << 4) + (u0 << 1);
        {
            unsigned int* dst =
                (unsigned int*)(nxt + ((size_t)(ug0 >> 3) * 256 + B0 + bb) * 8 + (ug0 & 7));
            __hip_atomic_store(dst, hs.u, __ATOMIC_RELAXED, __HIP_MEMORY_SCOPE_AGENT);
        }
        if (t == T_STEPS - 1) {
            f32x2 hv2; hv2[0] = hvf[0]; hv2[1] = hvf[1];
            *(f32x2*)&hfinal[(size_t)(B0 + bb) * HID + ug0] = hv2;
            break;  // no barrier after last step
        }

        // ---- grid barrier: own h-stores ack'd, then arrive; overlap x-prep; spin ----
        asm volatile("s_waitcnt vmcnt(0)" ::: "memory");
        __syncthreads();
        if (tid == 0)
            __hip_atomic_store(bar + (wg << 4), (unsigned int)(t + 1), __ATOMIC_RELAXED,
                               __HIP_MEMORY_SCOPE_AGENT);
        // reset acc and fold in x(t+1) while other WGs arrive
#pragma unroll
        for (int i = 0; i < 4; i++)
#pragma unroll
            for (int j = 0; j < 4; j++) acc[i][j] = (f32x4){0.f, 0.f, 0.f, 0.f};
        XPREP(t + 1);
        if (tid >= 256) {
            const unsigned int* ap = bar + ((tid - 256) << 4);
            while (__hip_atomic_load(ap, __ATOMIC_RELAXED, __HIP_MEMORY_SCOPE_AGENT) <
                   (unsigned int)(t + 1)) {
                __builtin_amdgcn_s_sleep(1);
            }
        }
        __syncthreads();
    }
}

// out[b][j] = bout[j] + sum_k hfinal[b][k] * Wout[k][j]   (256 blocks x 64 threads)
__global__ void proj_kernel(const float* __restrict__ hfinal, const float* __restrict__ Wout,
                            const float* __restrict__ bout, float* __restrict__ out) {
    int b = blockIdx.x;
    int l = threadIdx.x;
    float acc[24];
#pragma unroll
    for (int j = 0; j < 24; j++) acc[j] = 0.f;
    for (int i = 0; i < 16; i++) {
        int k = i * 64 + l;
        float h = hfinal[(size_t)b * HID + k];
        const float* wr = Wout + (size_t)k * 24;
#pragma unroll
        for (int j = 0; j < 24; j++) acc[j] += h * wr[j];
    }
    __shared__ float red[24][65];
#pragma unroll
    for (int j = 0; j < 24; j++) red[j][l] = acc[j];
    __syncthreads();
    if (l < 24) {
        float s = bout[l];
#pragma unroll
        for (int i = 0; i < 64; i++) s += red[l][i];
        out[b * 24 + l] = s;
    }
}

extern "C" void kernel_launch(void* const* d_in, const int* in_sizes, int n_in,
                              void* d_out, int out_size, void* d_ws, size_t ws_size,
                              hipStream_t stream) {
    const float* x = (const float*)d_in[0];     // [256][512][64]
    const float* W = (const float*)d_in[1];     // [1088][4096]
    const float* b = (const float*)d_in[2];     // [4096]
    const float* Wout = (const float*)d_in[3];  // [1024][24]
    const float* bout = (const float*)d_in[4];  // [24]
    float* out = (float*)d_out;

    char* ws = (char*)d_ws;
    _Float16* Wp = (_Float16*)ws;                                 // 8,912,896 B
    _Float16* hbuf = (_Float16*)(ws + 8912896);                   // 1,048,576 B
    float* hfinal = (float*)(ws + 8912896 + 1048576);             // 1,048,576 B
    unsigned int* bar = (unsigned int*)(ws + 8912896 + 2097152);  // 16,384 B

    // zero h buffer 0 (h_init = 0) and barrier words, every call (graph-replay safe)
    hipMemsetAsync(hbuf, 0, (size_t)128 * 256 * 8 * sizeof(_Float16), stream);
    hipMemsetAsync(bar, 0, 16384, stream);

    pack_w<<<(64 * 136 * 64 + 255) / 256, 256, 0, stream>>>(W, Wp);

    void* args[6];
    args[0] = (void*)&x;
    args[1] = (void*)&Wp;
    args[2] = (void*)&b;
    args[3] = (void*)&hbuf;
    args[4] = (void*)&hfinal;
    args[5] = (void*)&bar;
    hipLaunchCooperativeKernel((void*)lstm_persist, dim3(GRID), dim3(NTHR), args, 0, stream);

    proj_kernel<<<256, 64, 0, stream>>>(hfinal, Wout, bout, out);
}